// Round 4
// baseline (178.529 us; speedup 1.0000x reference)
//
#include <hip/hip_runtime.h>
#include <hip/hip_bf16.h>

// LIF neuron forward scan.
// x_seq: (T=64, B=32, F=8192) fp32. Outputs: spike_seq then mem_seq (T,B,F),
// concatenated flat in d_out.
//
// Recurrence per (b,f):
//   mem = mem * 0.5 + x      (tau_mem=2 -> 1-decay=0.5; dt=1)
//   spike = (mem >= 1) ? 1 : 0
//   mem = spike ? 0 : mem
//
// Memory-bound: 201 MB traffic -> ~33 us floor at 6.3 TB/s.
// R4: R3's ping-pong prefetch pipeline, with clang ext_vector_type(4) so the
// nontemporal builtins accept the pointers (HIP float4 is a struct -> rejected).

#define T_STEPS 64
#define BF (32 * 8192)          // elements per timestep
#define BF4 (BF / 4)            // 65536 float4 columns
#define GRP 8                   // timesteps per pipeline stage

typedef float v4f __attribute__((ext_vector_type(4)));

__global__ __launch_bounds__(256) void lif_fwd_kernel(
    const v4f* __restrict__ x,
    v4f* __restrict__ spike_out,
    v4f* __restrict__ mem_out)
{
    const int idx = blockIdx.x * blockDim.x + threadIdx.x;  // 0 .. BF4-1
    const v4f* xp = x + idx;
    v4f* so = spike_out + idx;
    v4f* mo = mem_out + idx;

    v4f mem = {0.f, 0.f, 0.f, 0.f};
    v4f buf[2][GRP];

    // prologue: load group 0
#pragma unroll
    for (int j = 0; j < GRP; ++j)
        buf[0][j] = xp[(size_t)j * BF4];

#pragma unroll
    for (int g = 0; g < T_STEPS / GRP; ++g) {
        const int cur = g & 1;
        const int nxt = cur ^ 1;

        // prefetch group g+1 while group g's compute/stores run
        if (g + 1 < T_STEPS / GRP) {
#pragma unroll
            for (int j = 0; j < GRP; ++j)
                buf[nxt][j] = xp[(size_t)((g + 1) * GRP + j) * BF4];
        }

#pragma unroll
        for (int j = 0; j < GRP; ++j) {
            const int t = g * GRP + j;
            const v4f xv = buf[cur][j];

            v4f m;
            m.x = mem.x * 0.5f + xv.x;
            m.y = mem.y * 0.5f + xv.y;
            m.z = mem.z * 0.5f + xv.z;
            m.w = mem.w * 0.5f + xv.w;

            v4f sp;
            sp.x = (m.x >= 1.0f) ? 1.0f : 0.0f;
            sp.y = (m.y >= 1.0f) ? 1.0f : 0.0f;
            sp.z = (m.z >= 1.0f) ? 1.0f : 0.0f;
            sp.w = (m.w >= 1.0f) ? 1.0f : 0.0f;

            m.x = (sp.x != 0.0f) ? 0.0f : m.x;
            m.y = (sp.y != 0.0f) ? 0.0f : m.y;
            m.z = (sp.z != 0.0f) ? 0.0f : m.z;
            m.w = (sp.w != 0.0f) ? 0.0f : m.w;

            mem = m;

            __builtin_nontemporal_store(sp, &so[(size_t)t * BF4]);
            __builtin_nontemporal_store(m,  &mo[(size_t)t * BF4]);
        }
    }
}

extern "C" void kernel_launch(void* const* d_in, const int* in_sizes, int n_in,
                              void* d_out, int out_size, void* d_ws, size_t ws_size,
                              hipStream_t stream) {
    const v4f* x = (const v4f*)d_in[0];
    v4f* spike_out = (v4f*)d_out;
    v4f* mem_out   = (v4f*)d_out + (size_t)T_STEPS * BF4;

    lif_fwd_kernel<<<BF4 / 256, 256, 0, stream>>>(x, spike_out, mem_out);
}